// Round 11
// baseline (190.709 us; speedup 1.0000x reference)
//
#include <hip/hip_runtime.h>
#include <hip/hip_bf16.h>

#define NB 32
#define DIN 512
#define TT 4096
#define DH 500
#define DHP 512
#define EPSV 1e-12f
#define BM 128             // t per block
#define LDA 520            // bf16 elems; 1040B row stride, 16B-aligned rows
#define NTILES (TT / BM)   // 32 t-tiles per batch
#define CHD 128            // d per chunk
#define NCHK 4             // 512 / CHD
#define KSC 8              // k-steps per chunk (CHD/16)

typedef short short8 __attribute__((ext_vector_type(8)));
typedef float f32x16 __attribute__((ext_vector_type(16)));
typedef float f32x4 __attribute__((ext_vector_type(4)));

__device__ inline unsigned short f2bf(float f) {
    unsigned int u = __builtin_bit_cast(unsigned int, f);
    unsigned int r = (u + 0x7fffu + ((u >> 16) & 1u)) >> 16;
    return (unsigned short)r;
}
__device__ inline float bf2f(unsigned short h) {
    unsigned int u = ((unsigned int)h) << 16;
    return __builtin_bit_cast(float, u);
}

// Kernel 0: pack w1 -> bf16 MFMA-fragment order [hb=16][ks=32][lane=64][8]
//   h = hb*32 + (lane&31),  d = ks*16 + (lane>>5)*8 + j
__global__ void prep_kernel(const float* __restrict__ w1, const float* __restrict__ w2,
                            unsigned short* __restrict__ w1b, float* __restrict__ w2f) {
    int idx = blockIdx.x * blockDim.x + threadIdx.x;
    if (idx < DHP * DIN) {
        const int j    = idx & 7;
        const int lane = (idx >> 3) & 63;
        const int ks   = (idx >> 9) & 31;
        const int hb   = idx >> 14;
        const int h = hb * 32 + (lane & 31);
        const int d = ks * 16 + (lane >> 5) * 8 + j;
        float v = (h < DH) ? w1[h * DIN + d] : 0.f;
        w1b[idx] = f2bf(v);
        if (idx < DHP) w2f[idx] = (idx < DH) ? w2[idx] : 0.f;
    }
}

// Kernel 1 (fused): one block per 128-t tile, 4 d-chunks, real pipeline:
//   [issue w1b(c+1) -> regs][issue x(c+1) float4][MFMA(c): ZERO vmcnt waits]
//   [wait + cvt + b128-write x(c+1)] barrier.
// Issue order matters: vmcnt is in-order; w1b before x means no MFMA drain.
__launch_bounds__(512, 2)
__global__ void scores_fused(const float* __restrict__ x,
                             const unsigned short* __restrict__ w1b,
                             const float* __restrict__ w2f,
                             float* __restrict__ pm, float* __restrict__ pz,
                             float* __restrict__ pswx, float* __restrict__ psx,
                             float* __restrict__ psx2) {
    __shared__ unsigned short A_lds[BM][LDA];
    __shared__ float score_p[8][BM];
    __shared__ float w_lds[BM];
    __shared__ float red[4];

    const int tid = threadIdx.x;
    const int b  = blockIdx.x >> 5;            // 32 tiles per batch
    const int t0 = (blockIdx.x & 31) * BM;

    // staging coords: q = t-quad (t = 4q..4q+3), dr = d-octet (d = dr*8+j)
    const int q  = tid & 31;
    const int dr = tid >> 5;                   // 0..15
    const float* xq = x + (size_t)b * DIN * TT + t0 + 4 * q;

    // MFMA coords
    const int w = tid >> 6;                    // wave: h-panels {2w,2w+1}
    const int lane = tid & 63;
    const int lane31 = lane & 31;
    const int khalf = lane >> 5;
    const int hrow0 = w * 64;
    const unsigned short* base0 = w1b + (size_t)w * 32768 + (size_t)lane * 8;
    const unsigned short* base1 = base0 + 16384;

    short8 a0p[2][KSC], a1p[2][KSC];           // w1b double-buffer (static idx)
    f32x16 acc[2][4];
    #pragma unroll
    for (int p = 0; p < 2; ++p)
        #pragma unroll
        for (int tt = 0; tt < 4; ++tt)
            #pragma unroll
            for (int g = 0; g < 16; ++g) acc[p][tt][g] = 0.f;

    // ---- Prologue: issue w1b(0), then stage chunk 0 ----
    #pragma unroll
    for (int j = 0; j < KSC; ++j) {
        a0p[0][j] = *reinterpret_cast<const short8*>(base0 + j * 512);
        a1p[0][j] = *reinterpret_cast<const short8*>(base1 + j * 512);
    }
    __builtin_amdgcn_sched_barrier(0);
    {
        f32x4 xv[8];
        #pragma unroll
        for (int j = 0; j < 8; ++j)
            xv[j] = *reinterpret_cast<const f32x4*>(xq + (size_t)(dr * 8 + j) * TT);
        __builtin_amdgcn_sched_barrier(0);
        #pragma unroll
        for (int i = 0; i < 4; ++i) {
            short8 pk;
            #pragma unroll
            for (int j = 0; j < 8; ++j) pk[j] = (short)f2bf(xv[j][i]);
            *reinterpret_cast<short8*>(&A_lds[4 * q + i][dr * 8]) = pk;
        }
    }
    __syncthreads();

    // ---- Pipelined main loop over d-chunks ----
    #pragma unroll
    for (int c = 0; c < NCHK; ++c) {
        const int cb = c & 1;
        f32x4 xv[8];
        if (c + 1 < NCHK) {
            // (A) issue w1b(c+1) FIRST (older in vmcnt queue than x)
            #pragma unroll
            for (int j = 0; j < KSC; ++j) {
                a0p[cb ^ 1][j] = *reinterpret_cast<const short8*>(base0 + ((c + 1) * KSC + j) * 512);
                a1p[cb ^ 1][j] = *reinterpret_cast<const short8*>(base1 + ((c + 1) * KSC + j) * 512);
            }
            __builtin_amdgcn_sched_barrier(0);
            // (B) issue x(c+1) float4 loads (1 KB/wave-instr, stay in flight)
            #pragma unroll
            for (int j = 0; j < 8; ++j)
                xv[j] = *reinterpret_cast<const f32x4*>(xq + (size_t)((c + 1) * CHD + dr * 8 + j) * TT);
        }
        __builtin_amdgcn_sched_barrier(0);
        // (C) MFMA(c): a-frags already resident (drained by prev iter's (D))
        #pragma unroll
        for (int ks = 0; ks < KSC; ++ks) {
            const int k = c * KSC + ks;
            #pragma unroll
            for (int tt = 0; tt < 4; ++tt) {
                short8 bb = *reinterpret_cast<const short8*>(
                    &A_lds[tt * 32 + lane31][k * 16 + khalf * 8]);
                acc[0][tt] = __builtin_amdgcn_mfma_f32_32x32x16_bf16(a0p[cb][ks], bb, acc[0][tt], 0, 0, 0);
                acc[1][tt] = __builtin_amdgcn_mfma_f32_32x32x16_bf16(a1p[cb][ks], bb, acc[1][tt], 0, 0, 0);
            }
        }
        __builtin_amdgcn_sched_barrier(0);
        // (D) wait x(c+1), convert, conflict-free b128 row writes
        if (c + 1 < NCHK) {
            #pragma unroll
            for (int i = 0; i < 4; ++i) {
                short8 pk;
                #pragma unroll
                for (int j = 0; j < 8; ++j) pk[j] = (short)f2bf(xv[j][i]);
                *reinterpret_cast<short8*>(&A_lds[4 * q + i][(c + 1) * CHD + dr * 8]) = pk;
            }
        }
        __syncthreads();
    }

    // ---- score reduce: relu*w2 over h (in-lane rows), per t-tile ----
    #pragma unroll
    for (int tt = 0; tt < 4; ++tt) {
        float s = 0.f;
        #pragma unroll
        for (int g = 0; g < 16; ++g) {
            const int rp = (g & 3) + 8 * (g >> 2) + 4 * khalf;
            s += fmaxf(acc[0][tt][g], 0.f) * w2f[hrow0 + rp]
               + fmaxf(acc[1][tt][g], 0.f) * w2f[hrow0 + 32 + rp];
        }
        s += __shfl_xor(s, 32, 64);
        if (khalf == 0) score_p[w][tt * 32 + lane31] = s;
    }
    __syncthreads();

    // ---- softmax partial over the tile's 128 t (threads 0..127) ----
    const int tl = tid & 127;
    float sv = 0.f;
    if (tid < BM) {
        #pragma unroll
        for (int ww = 0; ww < 8; ++ww) sv += score_p[ww][tl];
    }
    float m = (tid < BM) ? sv : -1e30f;
    #pragma unroll
    for (int k = 1; k <= 32; k <<= 1) m = fmaxf(m, __shfl_xor(m, k, 64));
    if (tid == 0) red[0] = m;
    if (tid == 64) red[1] = m;
    __syncthreads();
    const float mb = fmaxf(red[0], red[1]);
    float e = 0.f, Zp = 0.f;
    if (tid < BM) { e = __expf(sv - mb); Zp = e; }
    #pragma unroll
    for (int k = 1; k <= 32; k <<= 1) Zp += __shfl_xor(Zp, k, 64);
    if (tid == 0) red[2] = Zp;
    if (tid == 64) red[3] = Zp;
    if (tid < BM) w_lds[tl] = e;
    __syncthreads();
    if (tid == 0) { pm[blockIdx.x] = mb; pz[blockIdx.x] = red[2] + red[3]; }

    // ---- phase 4 (vectorized): wave w owns d in [64w,64w+64) ----
    // lane = (o = d-octet, g = t-group of 16); b128 reads, shfl-tree over g.
    {
        const int o = lane & 7;
        const int g = lane >> 3;
        float sx8[8], sx28[8], swx8[8];
        #pragma unroll
        for (int e2 = 0; e2 < 8; ++e2) { sx8[e2] = 0.f; sx28[e2] = 0.f; swx8[e2] = 0.f; }
        #pragma unroll
        for (int t5 = 0; t5 < 16; ++t5) {
            const int t = g * 16 + t5;
            short8 xv8 = *reinterpret_cast<const short8*>(&A_lds[t][w * 64 + o * 8]);
            const float wv = w_lds[t];
            #pragma unroll
            for (int e2 = 0; e2 < 8; ++e2) {
                const float f = bf2f((unsigned short)xv8[e2]);
                sx8[e2] += f; sx28[e2] += f * f; swx8[e2] += wv * f;
            }
        }
        #pragma unroll
        for (int mk = 8; mk <= 32; mk <<= 1) {
            #pragma unroll
            for (int e2 = 0; e2 < 8; ++e2) {
                sx8[e2]  += __shfl_xor(sx8[e2],  mk, 64);
                sx28[e2] += __shfl_xor(sx28[e2], mk, 64);
                swx8[e2] += __shfl_xor(swx8[e2], mk, 64);
            }
        }
        if (g == 0) {
            const size_t ob = (size_t)blockIdx.x * DHP + w * 64 + o * 8;
            #pragma unroll
            for (int e2 = 0; e2 < 8; ++e2) {
                psx[ob + e2]  = sx8[e2];
                psx2[ob + e2] = sx28[e2];
                pswx[ob + e2] = swx8[e2];
            }
        }
    }
}

// Kernel 2: combine 32 tiles per batch -> mean, stddev
__global__ void combine_kernel(const float* __restrict__ pm, const float* __restrict__ pz,
                               const float* __restrict__ pswx, const float* __restrict__ psx,
                               const float* __restrict__ psx2, float* __restrict__ out) {
    __shared__ float sm[NTILES], sz[NTILES];
    const int b = blockIdx.x;
    const int tid = threadIdx.x;               // d = tid, 0..511
    if (tid < NTILES) { sm[tid] = pm[b * NTILES + tid]; sz[tid] = pz[b * NTILES + tid]; }
    __syncthreads();

    float mg = -1e30f;
    #pragma unroll 8
    for (int i = 0; i < NTILES; ++i) mg = fmaxf(mg, sm[i]);
    float denom = 0.f;
    #pragma unroll 8
    for (int i = 0; i < NTILES; ++i) denom += sz[i] * __expf(sm[i] - mg);

    float num = 0.f, sx = 0.f, sx2 = 0.f;
    #pragma unroll 4
    for (int i = 0; i < NTILES; ++i) {
        const size_t o = ((size_t)(b * NTILES + i)) * DHP + tid;
        const float f = __expf(sm[i] - mg);
        num += f * pswx[o];
        sx  += psx[o];
        sx2 += psx2[o];
    }
    const float mean = num / denom;
    const float ex  = sx  * (1.f / TT);
    const float ex2 = sx2 * (1.f / TT);
    float var = ex2 - 2.f * mean * ex + mean * mean;
    if (var <= EPSV) var = EPSV;
    out[(size_t)b * 1024 + tid] = mean;
    out[(size_t)b * 1024 + 512 + tid] = sqrtf(var);
}

extern "C" void kernel_launch(void* const* d_in, const int* in_sizes, int n_in,
                              void* d_out, int out_size, void* d_ws, size_t ws_size,
                              hipStream_t stream) {
    const float* x  = (const float*)d_in[0];
    const float* w1 = (const float*)d_in[1];
    const float* w2 = (const float*)d_in[2];
    float* out = (float*)d_out;

    char* ws = (char*)d_ws;
    unsigned short* w1b = (unsigned short*)ws;                    // 512 KB
    float* w2f  = (float*)(ws + 524288);                          // 2 KB
    float* pm   = (float*)(ws + 526336);                          // 4 KB
    float* pz   = (float*)(ws + 530432);                          // 4 KB
    float* pswx = (float*)(ws + 534528);                          // 2 MB
    float* psx  = pswx + (size_t)NB * NTILES * DHP;               // 2 MB
    float* psx2 = psx  + (size_t)NB * NTILES * DHP;               // 2 MB

    prep_kernel<<<(DHP * DIN + 255) / 256, 256, 0, stream>>>(w1, w2, w1b, w2f);
    scores_fused<<<NB * NTILES, 512, 0, stream>>>(x, w1b, w2f, pm, pz, pswx, psx, psx2);
    combine_kernel<<<NB, 512, 0, stream>>>(pm, pz, pswx, psx, psx2, out);
}